// Round 1
// baseline (67.532 us; speedup 1.0000x reference)
//
#include <hip/hip_runtime.h>
#include <hip/hip_bf16.h>

#define EPS_F 1e-8f
#define MIN_THRESH_F 0.1f

// d_ws layout: ws[0] = float total, ((int*)ws)[1] = count

__global__ __launch_bounds__(256) void cosloss_main(
    const float* __restrict__ a, const float* __restrict__ b,
    const int* __restrict__ labels, int N, float* __restrict__ ws)
{
    const int lane = threadIdx.x & 63;
    const int wave = threadIdx.x >> 6;            // 0..3
    const int wavesPerBlock = blockDim.x >> 6;    // 4
    int row = blockIdx.x * wavesPerBlock + wave;
    const int rowStride = gridDim.x * wavesPerBlock;

    float total = 0.0f;
    int cnt = 0;

    for (; row < N; row += rowStride) {
        const long long base = (long long)labels[row] * 512LL;
        const float4* pa = (const float4*)(a + base);
        const float4* pb = (const float4*)(b + base);

        float ip = 0.0f, s1 = 0.0f, s2 = 0.0f;
        #pragma unroll
        for (int i = 0; i < 2; ++i) {
            float4 va = pa[lane + i * 64];
            float4 vb = pb[lane + i * 64];
            ip += va.x * vb.x + va.y * vb.y + va.z * vb.z + va.w * vb.w;
            s1 += va.x * va.x + va.y * va.y + va.z * va.z + va.w * va.w;
            s2 += vb.x * vb.x + vb.y * vb.y + vb.z * vb.z + vb.w * vb.w;
        }

        // 64-lane butterfly reduction
        #pragma unroll
        for (int off = 32; off >= 1; off >>= 1) {
            ip += __shfl_xor(ip, off);
            s1 += __shfl_xor(s1, off);
            s2 += __shfl_xor(s2, off);
        }

        if (lane == 0) {
            float w = sqrtf(s1) * sqrtf(s2);
            float c = ip / fmaxf(w, EPS_F);
            if (c >= MIN_THRESH_F) { total += c; cnt += 1; }
        }
    }

    // block-level reduction (lane 0 of each wave holds partials)
    __shared__ float s_total[8];
    __shared__ int   s_cnt[8];
    if (lane == 0) { s_total[wave] = total; s_cnt[wave] = cnt; }
    __syncthreads();
    if (threadIdx.x == 0) {
        float t = 0.0f; int c = 0;
        for (int i = 0; i < wavesPerBlock; ++i) { t += s_total[i]; c += s_cnt[i]; }
        atomicAdd(&ws[0], t);
        atomicAdd((int*)ws + 1, c);
    }
}

__global__ void cosloss_final(const float* __restrict__ ws, float* __restrict__ out)
{
    float total = ws[0];
    int cnt = ((const int*)ws)[1];
    if (cnt < 1) cnt = 1;
    out[0] = total / (float)cnt;
}

extern "C" void kernel_launch(void* const* d_in, const int* in_sizes, int n_in,
                              void* d_out, int out_size, void* d_ws, size_t ws_size,
                              hipStream_t stream)
{
    const float* a      = (const float*)d_in[0];
    const float* b      = (const float*)d_in[1];
    const int*   labels = (const int*)d_in[2];
    const int N = in_sizes[2];

    float* ws = (float*)d_ws;

    // zero the two accumulators (graph-capture legal)
    hipMemsetAsync(ws, 0, 2 * sizeof(float), stream);

    const int wavesPerBlock = 4;
    int blocks = (N + wavesPerBlock - 1) / wavesPerBlock;
    if (blocks > 2048) blocks = 2048;

    cosloss_main<<<blocks, 256, 0, stream>>>(a, b, labels, N, ws);
    cosloss_final<<<1, 1, 0, stream>>>(ws, (float*)d_out);
}

// Round 2
// 19.261 us; speedup vs baseline: 3.5062x; 3.5062x over previous
//
#include <hip/hip_runtime.h>
#include <hip/hip_bf16.h>

#define EPS_F 1e-8f
#define MIN_THRESH_F 0.1f

// d_ws layout: float2 partials[gridDim.x]  (total, count) per block.
// Every block writes its slot unconditionally every call -> deterministic,
// no zeroing needed, no atomics.

__global__ __launch_bounds__(256) void cosloss_main(
    const float* __restrict__ a, const float* __restrict__ b,
    const int* __restrict__ labels, int N, float2* __restrict__ partials)
{
    const int lane = threadIdx.x & 63;
    const int wave = threadIdx.x >> 6;            // 0..3
    const int nw   = gridDim.x << 2;              // total waves
    const int wid  = (blockIdx.x << 2) + wave;

    float total = 0.0f, cnt = 0.0f;

    for (int r0 = wid; r0 < N; r0 += 2 * nw) {
        const int r1 = r0 + nw;
        const bool v1 = r1 < N;

        // Load both labels first, then put all 8 data loads in flight.
        const long long base0 = (long long)labels[r0] * 512ll;
        const long long base1 = v1 ? (long long)labels[r1] * 512ll : 0ll;

        const float4* pa0 = (const float4*)(a + base0);
        const float4* pb0 = (const float4*)(b + base0);
        const float4* pa1 = (const float4*)(a + base1);
        const float4* pb1 = (const float4*)(b + base1);

        float4 a00 = pa0[lane], a01 = pa0[lane + 64];
        float4 b00 = pb0[lane], b01 = pb0[lane + 64];
        float4 a10 = pa1[lane], a11 = pa1[lane + 64];
        float4 b10 = pb1[lane], b11 = pb1[lane + 64];

        float ip0 = a00.x*b00.x + a00.y*b00.y + a00.z*b00.z + a00.w*b00.w
                  + a01.x*b01.x + a01.y*b01.y + a01.z*b01.z + a01.w*b01.w;
        float s10 = a00.x*a00.x + a00.y*a00.y + a00.z*a00.z + a00.w*a00.w
                  + a01.x*a01.x + a01.y*a01.y + a01.z*a01.z + a01.w*a01.w;
        float s20 = b00.x*b00.x + b00.y*b00.y + b00.z*b00.z + b00.w*b00.w
                  + b01.x*b01.x + b01.y*b01.y + b01.z*b01.z + b01.w*b01.w;

        float ip1 = a10.x*b10.x + a10.y*b10.y + a10.z*b10.z + a10.w*b10.w
                  + a11.x*b11.x + a11.y*b11.y + a11.z*b11.z + a11.w*b11.w;
        float s11 = a10.x*a10.x + a10.y*a10.y + a10.z*a10.z + a10.w*a10.w
                  + a11.x*a11.x + a11.y*a11.y + a11.z*a11.z + a11.w*a11.w;
        float s21 = b10.x*b10.x + b10.y*b10.y + b10.z*b10.z + b10.w*b10.w
                  + b11.x*b11.x + b11.y*b11.y + b11.z*b11.z + b11.w*b11.w;

        #pragma unroll
        for (int off = 32; off >= 1; off >>= 1) {
            ip0 += __shfl_xor(ip0, off);
            s10 += __shfl_xor(s10, off);
            s20 += __shfl_xor(s20, off);
            ip1 += __shfl_xor(ip1, off);
            s11 += __shfl_xor(s11, off);
            s21 += __shfl_xor(s21, off);
        }

        if (lane == 0) {
            float c0 = ip0 / fmaxf(sqrtf(s10) * sqrtf(s20), EPS_F);
            if (c0 >= MIN_THRESH_F) { total += c0; cnt += 1.0f; }
            if (v1) {
                float c1 = ip1 / fmaxf(sqrtf(s11) * sqrtf(s21), EPS_F);
                if (c1 >= MIN_THRESH_F) { total += c1; cnt += 1.0f; }
            }
        }
    }

    // block-level reduction (lane 0 of each wave holds partials), then one
    // unconditional partial write per block -- no atomics, no memset needed.
    __shared__ float s_total[4];
    __shared__ float s_cnt[4];
    if (lane == 0) { s_total[wave] = total; s_cnt[wave] = cnt; }
    __syncthreads();
    if (threadIdx.x == 0) {
        float t = s_total[0] + s_total[1] + s_total[2] + s_total[3];
        float c = s_cnt[0] + s_cnt[1] + s_cnt[2] + s_cnt[3];
        partials[blockIdx.x] = make_float2(t, c);
    }
}

__global__ __launch_bounds__(1024) void cosloss_final(
    const float2* __restrict__ partials, int M, float* __restrict__ out)
{
    float t = 0.0f, c = 0.0f;
    for (int i = threadIdx.x; i < M; i += 1024) {
        float2 p = partials[i];
        t += p.x; c += p.y;
    }
    #pragma unroll
    for (int off = 32; off >= 1; off >>= 1) {
        t += __shfl_xor(t, off);
        c += __shfl_xor(c, off);
    }
    __shared__ float st[16], sc[16];
    const int lane = threadIdx.x & 63, w = threadIdx.x >> 6;
    if (lane == 0) { st[w] = t; sc[w] = c; }
    __syncthreads();
    if (threadIdx.x == 0) {
        float T = 0.0f, C = 0.0f;
        #pragma unroll
        for (int i = 0; i < 16; ++i) { T += st[i]; C += sc[i]; }
        if (C < 1.0f) C = 1.0f;
        out[0] = T / C;
    }
}

extern "C" void kernel_launch(void* const* d_in, const int* in_sizes, int n_in,
                              void* d_out, int out_size, void* d_ws, size_t ws_size,
                              hipStream_t stream)
{
    const float* a      = (const float*)d_in[0];
    const float* b      = (const float*)d_in[1];
    const int*   labels = (const int*)d_in[2];
    const int N = in_sizes[2];

    float2* partials = (float2*)d_ws;

    const int blocks = 2048;   // 4 waves/block, 2 rows/wave covers N=16384
    cosloss_main<<<blocks, 256, 0, stream>>>(a, b, labels, N, partials);
    cosloss_final<<<1, 1024, 0, stream>>>(partials, blocks, (float*)d_out);
}

// Round 3
// 19.112 us; speedup vs baseline: 3.5334x; 1.0078x over previous
//
#include <hip/hip_runtime.h>
#include <hip/hip_bf16.h>

#define EPS_F 1e-8f
#define MIN_THRESH_F 0.1f

// One row per HALF-wave (32 lanes x 4 float4 = 512 floats = D).
// d_ws layout: float2 partials[gridDim.x] (total, count). Every block writes
// its slot unconditionally -> deterministic, no memset, no atomics.

__global__ __launch_bounds__(256) void cosloss_main(
    const float* __restrict__ a, const float* __restrict__ b,
    const int* __restrict__ labels, int N, float2* __restrict__ partials)
{
    const int lane = threadIdx.x & 63;
    const int wave = threadIdx.x >> 6;      // 0..3
    const int sub  = lane & 31;             // lane within half-wave
    const int half = lane >> 5;             // 0 or 1
    const int wid  = (blockIdx.x << 2) + wave;
    const int totalWaves = gridDim.x << 2;

    float total = 0.0f, cnt = 0.0f;

    for (int rb = wid * 2; rb < N; rb += totalWaves * 2) {
        const int r = rb + half;
        const bool valid = r < N;
        const int label = labels[valid ? r : 0];

        const char* pa = (const char*)a + ((long long)label << 11) + (sub << 4);
        const char* pb = (const char*)b + ((long long)label << 11) + (sub << 4);

        float4 a0 = *(const float4*)(pa);
        float4 a1 = *(const float4*)(pa + 512);
        float4 a2 = *(const float4*)(pa + 1024);
        float4 a3 = *(const float4*)(pa + 1536);
        float4 b0 = *(const float4*)(pb);
        float4 b1 = *(const float4*)(pb + 512);
        float4 b2 = *(const float4*)(pb + 1024);
        float4 b3 = *(const float4*)(pb + 1536);

        float ip = a0.x*b0.x + a0.y*b0.y + a0.z*b0.z + a0.w*b0.w
                 + a1.x*b1.x + a1.y*b1.y + a1.z*b1.z + a1.w*b1.w
                 + a2.x*b2.x + a2.y*b2.y + a2.z*b2.z + a2.w*b2.w
                 + a3.x*b3.x + a3.y*b3.y + a3.z*b3.z + a3.w*b3.w;
        float s1 = a0.x*a0.x + a0.y*a0.y + a0.z*a0.z + a0.w*a0.w
                 + a1.x*a1.x + a1.y*a1.y + a1.z*a1.z + a1.w*a1.w
                 + a2.x*a2.x + a2.y*a2.y + a2.z*a2.z + a2.w*a2.w
                 + a3.x*a3.x + a3.y*a3.y + a3.z*a3.z + a3.w*a3.w;
        float s2 = b0.x*b0.x + b0.y*b0.y + b0.z*b0.z + b0.w*b0.w
                 + b1.x*b1.x + b1.y*b1.y + b1.z*b1.z + b1.w*b1.w
                 + b2.x*b2.x + b2.y*b2.y + b2.z*b2.z + b2.w*b2.w
                 + b3.x*b3.x + b3.y*b3.y + b3.z*b3.z + b3.w*b3.w;

        // 5-step butterfly within the 32-lane half (xor masks <= 16 stay
        // inside the half); both halves reduce their own row simultaneously.
        #pragma unroll
        for (int off = 16; off >= 1; off >>= 1) {
            ip += __shfl_xor(ip, off);
            s1 += __shfl_xor(s1, off);
            s2 += __shfl_xor(s2, off);
        }

        if (sub == 0 && valid) {
            float c = ip / fmaxf(sqrtf(s1) * sqrtf(s2), EPS_F);
            if (c >= MIN_THRESH_F) { total += c; cnt += 1.0f; }
        }
    }

    __shared__ float st[8], sc[8];
    if (sub == 0) { st[(wave << 1) + half] = total; sc[(wave << 1) + half] = cnt; }
    __syncthreads();
    if (threadIdx.x == 0) {
        float t = 0.0f, c = 0.0f;
        #pragma unroll
        for (int i = 0; i < 8; ++i) { t += st[i]; c += sc[i]; }
        partials[blockIdx.x] = make_float2(t, c);
    }
}

__global__ __launch_bounds__(256) void cosloss_final(
    const float4* __restrict__ partials4, int M4, float* __restrict__ out)
{
    float t = 0.0f, c = 0.0f;
    for (int i = threadIdx.x; i < M4; i += 256) {
        float4 p = partials4[i];           // two float2 partials
        t += p.x + p.z;
        c += p.y + p.w;
    }
    #pragma unroll
    for (int off = 32; off >= 1; off >>= 1) {
        t += __shfl_xor(t, off);
        c += __shfl_xor(c, off);
    }
    __shared__ float st[4], sc[4];
    const int lane = threadIdx.x & 63, w = threadIdx.x >> 6;
    if (lane == 0) { st[w] = t; sc[w] = c; }
    __syncthreads();
    if (threadIdx.x == 0) {
        float T = st[0] + st[1] + st[2] + st[3];
        float C = sc[0] + sc[1] + sc[2] + sc[3];
        if (C < 1.0f) C = 1.0f;
        out[0] = T / C;
    }
}

extern "C" void kernel_launch(void* const* d_in, const int* in_sizes, int n_in,
                              void* d_out, int out_size, void* d_ws, size_t ws_size,
                              hipStream_t stream)
{
    const float* a      = (const float*)d_in[0];
    const float* b      = (const float*)d_in[1];
    const int*   labels = (const int*)d_in[2];
    const int N = in_sizes[2];

    float2* partials = (float2*)d_ws;

    const int blocks = 2048;   // 4 waves x 2 rows each -> covers N=16384 in one pass
    cosloss_main<<<blocks, 256, 0, stream>>>(a, b, labels, N, partials);
    cosloss_final<<<1, 256, 0, stream>>>((const float4*)partials, blocks / 2,
                                         (float*)d_out);
}